// Round 5
// baseline (608.951 us; speedup 1.0000x reference)
//
#include <hip/hip_runtime.h>

// Problem constants
#define CN1 262144
#define CN2 65536
#define CK  16
#define CM  (CN2*CK)   // 1048576

typedef unsigned short u16;
typedef unsigned int   u32;

__device__ __forceinline__ float b2f(u16 h) {
    union { u32 u; float f; } v; v.u = ((u32)h) << 16; return v.f;
}
__device__ __forceinline__ u16 f2b(float f) {
    union { float f; u32 u; } v; v.f = f;
    u32 lsb = (v.u >> 16) & 1u;
    return (u16)((v.u + 0x7FFFu + lsb) >> 16);
}

// float-element offsets into the prepped weight block (all f32)
#define W_POS   0        // ws1[:,0:3]   64*3
#define W_FEAT  256      // ws1[:,3:67]  64*64 row-major [j][i]
#define W_AS    12544    // shrinker BN scale (64)
#define W_BS    12608    // shrinker BN offset incl. bs1 (64)
#define W_WS2   12672    // ws2 row (64)
#define W_A2    12736    // linear2 BN scale (64)
#define W_B2    12800    // linear2 BN offset incl. b2 (64)
#define W_A1    12864    // linear1 BN scale (64)
#define W_B1    12928    // linear1 BN offset incl. b1 (64)
#define W_BS2   12992    // bs2 scalar
#define W_MODE  13000    // u32 slot: 1 = tensors are bf16, 0 = tensors are f32
#define W_W1T   13056    // w1 transposed [i][c] (4096)
#define W_W2T   17152    // w2 transposed [i][c] (4096)

// runtime-dtype scalar load
__device__ __forceinline__ float ldv(const void* p, size_t i, int bf) {
    return bf ? b2f(((const u16*)p)[i]) : ((const float*)p)[i];
}

// runtime-dtype 64-channel row load (per-thread)
__device__ __forceinline__ void load_row64(const void* p, size_t row, int bf, float* xr) {
    if (bf) {
        const uint4* xv = (const uint4*)((const u16*)p + row * 64);
        #pragma unroll
        for (int q = 0; q < 8; q++) {
            uint4 u = xv[q];
            u32 w[4] = {u.x, u.y, u.z, u.w};
            #pragma unroll
            for (int e = 0; e < 4; e++) {
                xr[q*8 + e*2 + 0] = b2f((u16)(w[e] & 0xffffu));
                xr[q*8 + e*2 + 1] = b2f((u16)(w[e] >> 16));
            }
        }
    } else {
        const float4* xv = (const float4*)((const float*)p + row * 64);
        #pragma unroll
        for (int q = 0; q < 16; q++) {
            float4 u = xv[q];
            xr[q*4+0] = u.x; xr[q*4+1] = u.y; xr[q*4+2] = u.z; xr[q*4+3] = u.w;
        }
    }
}

// ---------------------------------------------------------------------------
// k_prep: detect tensor dtype from g1 (= exact ones), convert weights -> f32
// (incl. transposed w1/w2), fold BN+bias into per-channel affine.
// ---------------------------------------------------------------------------
__global__ __launch_bounds__(256) void k_prep(
    const void* __restrict__ w1,  const void* __restrict__ b1,  const void* __restrict__ g1,
    const void* __restrict__ be1, const void* __restrict__ m1,  const void* __restrict__ v1,
    const void* __restrict__ w2,  const void* __restrict__ b2,  const void* __restrict__ g2,
    const void* __restrict__ be2, const void* __restrict__ m2,  const void* __restrict__ v2,
    const void* __restrict__ ws1, const void* __restrict__ bs1, const void* __restrict__ gs,
    const void* __restrict__ bes, const void* __restrict__ ms,  const void* __restrict__ vs,
    const void* __restrict__ ws2, const void* __restrict__ bs2, float* __restrict__ wb)
{
    u32 w0 = ((const u32*)g1)[0];
    int bf = (w0 != 0x3F800000u) ? 1 : 0;   // f32 ones word = 0x3F800000

    int tid = threadIdx.x;
    for (int t = tid; t < 64*67; t += 256) {
        int r = t / 67, c = t % 67;
        float v = ldv(ws1, t, bf);
        if (c < 3) wb[W_POS + r*3 + c] = v;
        else       wb[W_FEAT + r*64 + (c-3)] = v;
    }
    for (int t = tid; t < 64*64; t += 256) {
        // transposed: W_WxT[i*64+c] = wx[c][i];  t = i*64+c
        size_t src = (size_t)(t & 63) * 64 + (t >> 6);
        wb[W_W1T + t] = ldv(w1, src, bf);
        wb[W_W2T + t] = ldv(w2, src, bf);
    }
    if (tid < 64) {
        float as = ldv(gs, tid, bf) * rsqrtf(ldv(vs, tid, bf) + 1e-5f);
        wb[W_AS + tid] = as;
        wb[W_BS + tid] = (ldv(bs1, tid, bf) - ldv(ms, tid, bf)) * as + ldv(bes, tid, bf);
        wb[W_WS2 + tid] = ldv(ws2, tid, bf);
        float a2 = ldv(g2, tid, bf) * rsqrtf(ldv(v2, tid, bf) + 1e-5f);
        wb[W_A2 + tid] = a2;
        wb[W_B2 + tid] = (ldv(b2, tid, bf) - ldv(m2, tid, bf)) * a2 + ldv(be2, tid, bf);
        float a1 = ldv(g1, tid, bf) * rsqrtf(ldv(v1, tid, bf) + 1e-5f);
        wb[W_A1 + tid] = a1;
        wb[W_B1 + tid] = (ldv(b1, tid, bf) - ldv(m1, tid, bf)) * a1 + ldv(be1, tid, bf);
    }
    if (tid == 0) {
        wb[W_BS2] = ldv(bs2, 0, bf);
        ((u32*)wb)[W_MODE] = (u32)bf;
    }
}

__global__ __launch_bounds__(256) void k_zero(u32* __restrict__ offsets)
{
    offsets[blockIdx.x * 256 + threadIdx.x] = 0u;
}

// ---------------------------------------------------------------------------
// k_coarse: thread per coarse point n2 — shrinker logits for its K=16 pairs.
// Also folds the CSR degree-count atomics (saves a kernel + a knn pass).
// ---------------------------------------------------------------------------
__global__ __launch_bounds__(256) void k_coarse(
    const void* __restrict__ p1, const void* __restrict__ p2,
    const void* __restrict__ x2, const int* __restrict__ knn,
    const float* __restrict__ wb,
    float* __restrict__ logits, u32* __restrict__ offsets)
{
    int bf = (int)((const u32*)wb)[W_MODE];
    int n2 = blockIdx.x * 256 + threadIdx.x;

    float xr[64];
    load_row64(x2, (size_t)n2, bf, xr);

    float p2x = ldv(p2, (size_t)n2*3+0, bf);
    float p2y = ldv(p2, (size_t)n2*3+1, bf);
    float p2z = ldv(p2, (size_t)n2*3+2, bf);

    int idxs[16];
    const int4* kv = (const int4*)(knn + (size_t)n2 * 16);
    #pragma unroll
    for (int q = 0; q < 4; q++) {
        int4 t = kv[q];
        idxs[q*4+0] = t.x; idxs[q*4+1] = t.y; idxs[q*4+2] = t.z; idxs[q*4+3] = t.w;
    }
    #pragma unroll
    for (int k = 0; k < 16; k++) {
        atomicAdd(&offsets[idxs[k] & (CN1-1)], 1u);   // degree count
    }
    float prx[16], pry[16], prz[16];
    #pragma unroll
    for (int k = 0; k < 16; k++) {
        size_t b = (size_t)(idxs[k] & (CN1-1)) * 3;
        prx[k] = ldv(p1, b+0, bf) - p2x;
        pry[k] = ldv(p1, b+1, bf) - p2y;
        prz[k] = ldv(p1, b+2, bf) - p2z;
    }
    float lg[16];
    #pragma unroll
    for (int k = 0; k < 16; k++) lg[k] = 0.f;

    for (int j = 0; j < 64; j++) {
        const float* wf = wb + W_FEAT + j*64;   // uniform -> s_load
        float d0=0,d1=0,d2=0,d3=0;
        #pragma unroll
        for (int q = 0; q < 16; q++) {
            d0 = fmaf(xr[q*4+0], wf[q*4+0], d0);
            d1 = fmaf(xr[q*4+1], wf[q*4+1], d1);
            d2 = fmaf(xr[q*4+2], wf[q*4+2], d2);
            d3 = fmaf(xr[q*4+3], wf[q*4+3], d3);
        }
        float dot = (d0+d1)+(d2+d3);

        float w0  = wb[W_POS + j*3+0];
        float w1v = wb[W_POS + j*3+1];
        float w2v = wb[W_POS + j*3+2];
        float As = wb[W_AS+j], Bs = wb[W_BS+j], wc = wb[W_WS2+j];
        #pragma unroll
        for (int k = 0; k < 16; k++) {
            float pre = fmaf(prz[k], w2v, fmaf(pry[k], w1v, fmaf(prx[k], w0, dot)));
            float h = fmaxf(fmaf(pre, As, Bs), 0.f);
            lg[k] = fmaf(h, wc, lg[k]);
        }
    }
    float bias2 = wb[W_BS2];
    float4* lo = (float4*)(logits + (size_t)n2 * 16);
    #pragma unroll
    for (int q = 0; q < 4; q++) {
        float4 t;
        t.x = lg[q*4+0] + bias2; t.y = lg[q*4+1] + bias2;
        t.z = lg[q*4+2] + bias2; t.w = lg[q*4+3] + bias2;
        lo[q] = t;
    }
}

// ---------------------------------------------------------------------------
// k_up: wave per coarse point, lane = channel.
// upfeat[n2][c] = relu(A2[c]*dot(x2[n2],w2[c]) + B2[c]), stored bf16 coalesced.
// ---------------------------------------------------------------------------
#define UP_PTS 16   // points per wave
__global__ __launch_bounds__(256) void k_up(
    const void* __restrict__ x2, const float* __restrict__ wb,
    u16* __restrict__ upfeat)
{
    int bf   = (int)((const u32*)wb)[W_MODE];
    int lane = threadIdx.x & 63;
    int wid  = (blockIdx.x * 256 + threadIdx.x) >> 6;

    float wcol[64];
    #pragma unroll
    for (int i = 0; i < 64; i++) wcol[i] = wb[W_W2T + i*64 + lane];
    float A2 = wb[W_A2 + lane], B2 = wb[W_B2 + lane];

    for (int it = 0; it < UP_PTS; ++it) {
        int n2 = __builtin_amdgcn_readfirstlane(wid * UP_PTS + it);
        float dot = 0.f;
        if (bf) {
            const u32* xr32 = (const u32*)((const u16*)x2 + (size_t)n2 * 64);
            #pragma unroll
            for (int i = 0; i < 32; i++) {
                u32 w = xr32[i];
                dot = fmaf(b2f((u16)(w & 0xffffu)), wcol[2*i+0], dot);
                dot = fmaf(b2f((u16)(w >> 16)),     wcol[2*i+1], dot);
            }
        } else {
            const float* xrow = (const float*)x2 + (size_t)n2 * 64;
            #pragma unroll
            for (int i = 0; i < 64; i++) dot = fmaf(xrow[i], wcol[i], dot);
        }
        float uf = fmaxf(fmaf(dot, A2, B2), 0.f);
        upfeat[(size_t)n2 * 64 + lane] = f2b(uf);   // 128 B coalesced per wave
    }
}

// ---------------------------------------------------------------------------
// CSR scan + scatter (packed: offsets[n1] = start<<6 | count-in-progress)
// ---------------------------------------------------------------------------
__global__ __launch_bounds__(256) void k_scanA(
    u32* __restrict__ offsets, u32* __restrict__ bsum)
{
    __shared__ u32 s[256];
    int t = threadIdx.x;
    int i = blockIdx.x * 256 + t;
    u32 v = offsets[i];
    s[t] = v; __syncthreads();
    for (int off = 1; off < 256; off <<= 1) {
        u32 add = (t >= off) ? s[t-off] : 0u;
        __syncthreads();
        s[t] += add;
        __syncthreads();
    }
    offsets[i] = s[t] - v;
    if (t == 255) bsum[blockIdx.x] = s[255];
}

__global__ __launch_bounds__(256) void k_scanB(
    const u32* __restrict__ bsum, u32* __restrict__ boff)
{
    __shared__ u32 s[256];
    int t = threadIdx.x;
    u32 a0 = bsum[t*4+0], a1 = bsum[t*4+1], a2 = bsum[t*4+2], a3 = bsum[t*4+3];
    u32 tot = a0 + a1 + a2 + a3;
    s[t] = tot; __syncthreads();
    for (int off = 1; off < 256; off <<= 1) {
        u32 add = (t >= off) ? s[t-off] : 0u;
        __syncthreads();
        s[t] += add;
        __syncthreads();
    }
    u32 base = s[t] - tot;
    boff[t*4+0] = base;
    boff[t*4+1] = base + a0;
    boff[t*4+2] = base + a0 + a1;
    boff[t*4+3] = base + a0 + a1 + a2;
}

__global__ __launch_bounds__(256) void k_scanC(
    u32* __restrict__ offsets, const u32* __restrict__ boff)
{
    int i = blockIdx.x * 256 + threadIdx.x;
    offsets[i] = (offsets[i] + boff[blockIdx.x]) << 6;
}

__global__ __launch_bounds__(256) void k_scatter(
    const int* __restrict__ knn, u32* __restrict__ offsets, u32* __restrict__ csr)
{
    int m = blockIdx.x * 256 + threadIdx.x;
    int n1 = knn[m] & (CN1-1);
    u32 v = atomicAdd(&offsets[n1], 1u);
    u32 pos = (v >> 6) + (v & 63u);
    csr[pos & (CM-1)] = (u32)m;
}

// ---------------------------------------------------------------------------
// k_dense: wave per dense point n1, lane = channel.
// ---------------------------------------------------------------------------
#define DN_PTS 32   // points per wave
__global__ __launch_bounds__(256) void k_dense(
    const void* __restrict__ x1, const float* __restrict__ wb,
    const float* __restrict__ logits, const u16* __restrict__ upfeat,
    const u32* __restrict__ offsets, const u32* __restrict__ csr,
    void* __restrict__ out)
{
    int bf   = (int)((const u32*)wb)[W_MODE];
    int lane = threadIdx.x & 63;
    int wid  = (blockIdx.x * 256 + threadIdx.x) >> 6;

    float wcol[64];
    #pragma unroll
    for (int i = 0; i < 64; i++) wcol[i] = wb[W_W1T + i*64 + lane];
    float A1 = wb[W_A1 + lane], B1 = wb[W_B1 + lane];

    for (int it = 0; it < DN_PTS; ++it) {
        int n1 = __builtin_amdgcn_readfirstlane(wid * DN_PTS + it);
        u32 pk = offsets[n1];                       // uniform -> scalar load
        int d = (int)(pk & 63u);
        int start = (int)(pk >> 6);

        u32 me = 0; float le = -3.0e38f;
        if (lane < d) {
            me = csr[(u32)(start + lane) & (CM-1)] & (CM-1);
            le = logits[me];
        }
        float mx = le;
        #pragma unroll
        for (int s = 32; s; s >>= 1) mx = fmaxf(mx, __shfl_xor(mx, s, 64));
        float ex = (lane < d) ? __expf(le - mx) : 0.f;
        float dn = ex;
        #pragma unroll
        for (int s = 32; s; s >>= 1) dn += __shfl_xor(dn, s, 64);
        float invd = (d > 0) ? (1.f / dn) : 0.f;

        float acc = 0.f;
        for (int e = 0; e < d; ++e) {
            u32   ms  = __shfl(me, e, 64);
            float exs = __shfl(ex, e, 64);
            acc = fmaf(exs, b2f(upfeat[(size_t)(ms >> 4) * 64 + lane]), acc);
        }

        float dot = 0.f;
        if (bf) {
            const u32* xr32 = (const u32*)((const u16*)x1 + (size_t)n1 * 64);
            #pragma unroll
            for (int i = 0; i < 32; i++) {
                u32 w = xr32[i];
                dot = fmaf(b2f((u16)(w & 0xffffu)), wcol[2*i+0], dot);
                dot = fmaf(b2f((u16)(w >> 16)),     wcol[2*i+1], dot);
            }
        } else {
            const float* xrow = (const float*)x1 + (size_t)n1 * 64;
            #pragma unroll
            for (int i = 0; i < 64; i++) dot = fmaf(xrow[i], wcol[i], dot);
        }
        float y = fmaxf(fmaf(dot, A1, B1), 0.f);
        float r = fmaf(acc, invd, y);

        if (bf) ((u16*)out)[(size_t)n1 * 64 + lane] = f2b(r);
        else    ((float*)out)[(size_t)n1 * 64 + lane] = r;
    }
}

// ---------------------------------------------------------------------------
// Workspace layout (byte offsets) — total ~18.02 MiB:
//   wb      @ 0        (f32 weights incl. transposes + mode flag)
//   logits  @ 1  MiB   (4 MiB,  f32[M])
//   csr     @ 5  MiB   (4 MiB,  u32[M])
//   upfeat  @ 9  MiB   (8 MiB,  bf16[N2*64])
//   offsets @ 17 MiB   (1 MiB,  u32[N1], packed start<<6|count)
//   bsum    @ 18 MiB   (4 KiB)
//   boff    @ 18 MiB + 4 KiB (4 KiB)
// ---------------------------------------------------------------------------
extern "C" void kernel_launch(void* const* d_in, const int* in_sizes, int n_in,
                              void* d_out, int out_size, void* d_ws, size_t ws_size,
                              hipStream_t stream)
{
    (void)in_sizes; (void)n_in; (void)out_size; (void)ws_size;
    const void* p1   = d_in[0];
    const void* p2   = d_in[1];
    const void* x1   = d_in[2];
    const void* x2   = d_in[3];
    const int*  knn  = (const int*)d_in[4];
    const void* w1   = d_in[5];
    const void* b1   = d_in[6];
    const void* g1   = d_in[7];
    const void* be1  = d_in[8];
    const void* m1   = d_in[9];
    const void* v1   = d_in[10];
    const void* w2   = d_in[11];
    const void* b2   = d_in[12];
    const void* g2   = d_in[13];
    const void* be2  = d_in[14];
    const void* m2   = d_in[15];
    const void* v2   = d_in[16];
    const void* ws1  = d_in[17];
    const void* bs1  = d_in[18];
    const void* gs   = d_in[19];
    const void* bes  = d_in[20];
    const void* ms   = d_in[21];
    const void* vs   = d_in[22];
    const void* ws2w = d_in[23];
    const void* bs2  = d_in[24];

    char* ws = (char*)d_ws;
    float* wb      = (float*)(ws);
    float* logits  = (float*)(ws + ((size_t)1  << 20));
    u32*   csr     = (u32*)  (ws + ((size_t)5  << 20));
    u16*   upfeat  = (u16*)  (ws + ((size_t)9  << 20));
    u32*   offsets = (u32*)  (ws + ((size_t)17 << 20));
    u32*   bsum    = (u32*)  (ws + ((size_t)18 << 20));
    u32*   boff    = (u32*)  (ws + ((size_t)18 << 20) + 4096);

    // grids: k_up = N2 / (4 waves * UP_PTS)  = 65536/64  = 1024 blocks
    //        k_dense = N1 / (4 * DN_PTS)     = 262144/128 = 2048 blocks
    k_prep   <<<1,        256, 0, stream>>>(w1,b1,g1,be1,m1,v1,
                                            w2,b2,g2,be2,m2,v2,
                                            ws1,bs1,gs,bes,ms,vs,
                                            ws2w, bs2, wb);
    k_zero   <<<CN1/256,  256, 0, stream>>>(offsets);
    k_coarse <<<CN2/256,  256, 0, stream>>>(p1, p2, x2, knn, wb, logits, offsets);
    k_up     <<<CN2/(4*UP_PTS), 256, 0, stream>>>(x2, wb, upfeat);
    k_scanA  <<<CN1/256,  256, 0, stream>>>(offsets, bsum);
    k_scanB  <<<1,        256, 0, stream>>>(bsum, boff);
    k_scanC  <<<CN1/256,  256, 0, stream>>>(offsets, boff);
    k_scatter<<<CM/256,   256, 0, stream>>>(knn, offsets, csr);
    k_dense  <<<CN1/(4*DN_PTS), 256, 0, stream>>>(x1, wb, logits, upfeat, offsets, csr, d_out);
}

// Round 6
// 524.721 us; speedup vs baseline: 1.1605x; 1.1605x over previous
//
#include <hip/hip_runtime.h>

// Problem constants
#define CN1 262144
#define CN2 65536
#define CK  16
#define CM  (CN2*CK)   // 1048576

typedef unsigned short u16;
typedef unsigned int   u32;

__device__ __forceinline__ float b2f(u16 h) {
    union { u32 u; float f; } v; v.u = ((u32)h) << 16; return v.f;
}
__device__ __forceinline__ u16 f2b(float f) {
    union { float f; u32 u; } v; v.f = f;
    u32 lsb = (v.u >> 16) & 1u;
    return (u16)((v.u + 0x7FFFu + lsb) >> 16);
}

// float-element offsets into the prepped weight block (all f32)
#define W_POS   0        // ws1[:,0:3]   64*3
#define W_FEAT  256      // ws1[:,3:67]  64*64 row-major [j][i]
#define W_AS    12544    // shrinker BN scale (64)
#define W_BS    12608    // shrinker BN offset incl. bs1 (64)
#define W_WS2   12672    // ws2 row (64)
#define W_A2    12736    // linear2 BN scale (64)
#define W_B2    12800    // linear2 BN offset incl. b2 (64)
#define W_A1    12864    // linear1 BN scale (64)
#define W_B1    12928    // linear1 BN offset incl. b1 (64)
#define W_BS2   12992    // bs2 scalar
#define W_MODE  13000    // u32 slot: 1 = tensors are bf16, 0 = tensors are f32
#define W_W1    13056    // w1 row-major [c][i] (4096) — k_dense GEMV
#define W_W2T   17152    // w2 transposed [i][c] (4096) — k_up

// runtime-dtype scalar load
__device__ __forceinline__ float ldv(const void* p, size_t i, int bf) {
    return bf ? b2f(((const u16*)p)[i]) : ((const float*)p)[i];
}

// runtime-dtype 64-channel row load (per-thread)
__device__ __forceinline__ void load_row64(const void* p, size_t row, int bf, float* xr) {
    if (bf) {
        const uint4* xv = (const uint4*)((const u16*)p + row * 64);
        #pragma unroll
        for (int q = 0; q < 8; q++) {
            uint4 u = xv[q];
            u32 w[4] = {u.x, u.y, u.z, u.w};
            #pragma unroll
            for (int e = 0; e < 4; e++) {
                xr[q*8 + e*2 + 0] = b2f((u16)(w[e] & 0xffffu));
                xr[q*8 + e*2 + 1] = b2f((u16)(w[e] >> 16));
            }
        }
    } else {
        const float4* xv = (const float4*)((const float*)p + row * 64);
        #pragma unroll
        for (int q = 0; q < 16; q++) {
            float4 u = xv[q];
            xr[q*4+0] = u.x; xr[q*4+1] = u.y; xr[q*4+2] = u.z; xr[q*4+3] = u.w;
        }
    }
}

// ---------------------------------------------------------------------------
// k_prep: block 0 preps weights (dtype-detect via g1 == exact ones);
// blocks 1..N1/256 zero the offsets array; block 1 also zeros the cursor.
// ---------------------------------------------------------------------------
__global__ __launch_bounds__(256) void k_prep(
    const void* __restrict__ w1,  const void* __restrict__ b1,  const void* __restrict__ g1,
    const void* __restrict__ be1, const void* __restrict__ m1,  const void* __restrict__ v1,
    const void* __restrict__ w2,  const void* __restrict__ b2,  const void* __restrict__ g2,
    const void* __restrict__ be2, const void* __restrict__ m2,  const void* __restrict__ v2,
    const void* __restrict__ ws1, const void* __restrict__ bs1, const void* __restrict__ gs,
    const void* __restrict__ bes, const void* __restrict__ ms,  const void* __restrict__ vs,
    const void* __restrict__ ws2, const void* __restrict__ bs2, float* __restrict__ wb,
    u32* __restrict__ offsets, u32* __restrict__ cursor)
{
    int b = blockIdx.x;
    int tid = threadIdx.x;
    if (b > 0) {
        offsets[(b - 1) * 256 + tid] = 0u;
        if (b == 1 && tid == 0) *cursor = 0u;
        return;
    }

    u32 w0 = ((const u32*)g1)[0];
    int bf = (w0 != 0x3F800000u) ? 1 : 0;   // f32 ones word = 0x3F800000

    for (int t = tid; t < 64*67; t += 256) {
        int r = t / 67, c = t % 67;
        float v = ldv(ws1, t, bf);
        if (c < 3) wb[W_POS + r*3 + c] = v;
        else       wb[W_FEAT + r*64 + (c-3)] = v;
    }
    for (int t = tid; t < 64*64; t += 256) {
        // W_W2T[i*64+c] = w2[c][i];  t = i*64+c
        size_t srcT = (size_t)(t & 63) * 64 + (t >> 6);
        wb[W_W2T + t] = ldv(w2, srcT, bf);
        wb[W_W1  + t] = ldv(w1, t, bf);      // row-major copy
    }
    if (tid < 64) {
        float as = ldv(gs, tid, bf) * rsqrtf(ldv(vs, tid, bf) + 1e-5f);
        wb[W_AS + tid] = as;
        wb[W_BS + tid] = (ldv(bs1, tid, bf) - ldv(ms, tid, bf)) * as + ldv(bes, tid, bf);
        wb[W_WS2 + tid] = ldv(ws2, tid, bf);
        float a2 = ldv(g2, tid, bf) * rsqrtf(ldv(v2, tid, bf) + 1e-5f);
        wb[W_A2 + tid] = a2;
        wb[W_B2 + tid] = (ldv(b2, tid, bf) - ldv(m2, tid, bf)) * a2 + ldv(be2, tid, bf);
        float a1 = ldv(g1, tid, bf) * rsqrtf(ldv(v1, tid, bf) + 1e-5f);
        wb[W_A1 + tid] = a1;
        wb[W_B1 + tid] = (ldv(b1, tid, bf) - ldv(m1, tid, bf)) * a1 + ldv(be1, tid, bf);
    }
    if (tid == 0) {
        wb[W_BS2] = ldv(bs2, 0, bf);
        ((u32*)wb)[W_MODE] = (u32)bf;
    }
}

// ---------------------------------------------------------------------------
// k_coarse: thread per coarse point n2 — shrinker logits for its K=16 pairs
// + CSR degree-count atomics.
// ---------------------------------------------------------------------------
__global__ __launch_bounds__(256) void k_coarse(
    const void* __restrict__ p1, const void* __restrict__ p2,
    const void* __restrict__ x2, const int* __restrict__ knn,
    const float* __restrict__ wb,
    float* __restrict__ logits, u32* __restrict__ offsets)
{
    int bf = (int)((const u32*)wb)[W_MODE];
    int n2 = blockIdx.x * 256 + threadIdx.x;

    float xr[64];
    load_row64(x2, (size_t)n2, bf, xr);

    float p2x = ldv(p2, (size_t)n2*3+0, bf);
    float p2y = ldv(p2, (size_t)n2*3+1, bf);
    float p2z = ldv(p2, (size_t)n2*3+2, bf);

    int idxs[16];
    const int4* kv = (const int4*)(knn + (size_t)n2 * 16);
    #pragma unroll
    for (int q = 0; q < 4; q++) {
        int4 t = kv[q];
        idxs[q*4+0] = t.x; idxs[q*4+1] = t.y; idxs[q*4+2] = t.z; idxs[q*4+3] = t.w;
    }
    #pragma unroll
    for (int k = 0; k < 16; k++) {
        atomicAdd(&offsets[idxs[k] & (CN1-1)], 1u);   // degree count
    }
    float prx[16], pry[16], prz[16];
    #pragma unroll
    for (int k = 0; k < 16; k++) {
        size_t b = (size_t)(idxs[k] & (CN1-1)) * 3;
        prx[k] = ldv(p1, b+0, bf) - p2x;
        pry[k] = ldv(p1, b+1, bf) - p2y;
        prz[k] = ldv(p1, b+2, bf) - p2z;
    }
    float lg[16];
    #pragma unroll
    for (int k = 0; k < 16; k++) lg[k] = 0.f;

    for (int j = 0; j < 64; j++) {
        const float* wf = wb + W_FEAT + j*64;   // uniform -> s_load
        float d0=0,d1=0,d2=0,d3=0;
        #pragma unroll
        for (int q = 0; q < 16; q++) {
            d0 = fmaf(xr[q*4+0], wf[q*4+0], d0);
            d1 = fmaf(xr[q*4+1], wf[q*4+1], d1);
            d2 = fmaf(xr[q*4+2], wf[q*4+2], d2);
            d3 = fmaf(xr[q*4+3], wf[q*4+3], d3);
        }
        float dot = (d0+d1)+(d2+d3);

        float w0  = wb[W_POS + j*3+0];
        float w1v = wb[W_POS + j*3+1];
        float w2v = wb[W_POS + j*3+2];
        float As = wb[W_AS+j], Bs = wb[W_BS+j], wc = wb[W_WS2+j];
        #pragma unroll
        for (int k = 0; k < 16; k++) {
            float pre = fmaf(prz[k], w2v, fmaf(pry[k], w1v, fmaf(prx[k], w0, dot)));
            float h = fmaxf(fmaf(pre, As, Bs), 0.f);
            lg[k] = fmaf(h, wc, lg[k]);
        }
    }
    float bias2 = wb[W_BS2];
    float4* lo = (float4*)(logits + (size_t)n2 * 16);
    #pragma unroll
    for (int q = 0; q < 4; q++) {
        float4 t;
        t.x = lg[q*4+0] + bias2; t.y = lg[q*4+1] + bias2;
        t.z = lg[q*4+2] + bias2; t.w = lg[q*4+3] + bias2;
        lo[q] = t;
    }
}

// ---------------------------------------------------------------------------
// k_up: wave per coarse point, lane = channel; coalesced bf16 stores.
// ---------------------------------------------------------------------------
#define UP_PTS 16   // points per wave
__global__ __launch_bounds__(256) void k_up(
    const void* __restrict__ x2, const float* __restrict__ wb,
    u16* __restrict__ upfeat)
{
    int bf   = (int)((const u32*)wb)[W_MODE];
    int lane = threadIdx.x & 63;
    int wid  = (blockIdx.x * 256 + threadIdx.x) >> 6;

    float wcol[64];
    #pragma unroll
    for (int i = 0; i < 64; i++) wcol[i] = wb[W_W2T + i*64 + lane];
    float A2 = wb[W_A2 + lane], B2 = wb[W_B2 + lane];

    for (int it = 0; it < UP_PTS; ++it) {
        int n2 = __builtin_amdgcn_readfirstlane(wid * UP_PTS + it);
        float dot = 0.f;
        if (bf) {
            const u32* xr32 = (const u32*)((const u16*)x2 + (size_t)n2 * 64);
            #pragma unroll
            for (int i = 0; i < 32; i++) {
                u32 w = xr32[i];
                dot = fmaf(b2f((u16)(w & 0xffffu)), wcol[2*i+0], dot);
                dot = fmaf(b2f((u16)(w >> 16)),     wcol[2*i+1], dot);
            }
        } else {
            const float* xrow = (const float*)x2 + (size_t)n2 * 64;
            #pragma unroll
            for (int i = 0; i < 64; i++) dot = fmaf(xrow[i], wcol[i], dot);
        }
        float uf = fmaxf(fmaf(dot, A2, B2), 0.f);
        upfeat[(size_t)n2 * 64 + lane] = f2b(uf);   // 128 B coalesced per wave
    }
}

// ---------------------------------------------------------------------------
// k_scan: fused single-kernel exclusive allocation. Block-local scan + one
// atomic cursor bump for the block base. Segment ORDER is arbitrary (only
// disjointness matters for CSR correctness).
// offsets[i] <- (base + local_exclusive) << 6
// ---------------------------------------------------------------------------
__global__ __launch_bounds__(256) void k_scan(
    u32* __restrict__ offsets, u32* __restrict__ cursor)
{
    __shared__ u32 s[256];
    __shared__ u32 base;
    int t = threadIdx.x;
    int i = blockIdx.x * 256 + t;
    u32 v = offsets[i];
    s[t] = v; __syncthreads();
    for (int off = 1; off < 256; off <<= 1) {
        u32 add = (t >= off) ? s[t-off] : 0u;
        __syncthreads();
        s[t] += add;
        __syncthreads();
    }
    u32 inc = s[t];                       // inclusive scan
    if (t == 255) base = atomicAdd(cursor, inc);
    __syncthreads();
    offsets[i] = (base + inc - v) << 6;
}

__global__ __launch_bounds__(256) void k_scatter(
    const int* __restrict__ knn, u32* __restrict__ offsets, u32* __restrict__ csr)
{
    int m = blockIdx.x * 256 + threadIdx.x;
    int n1 = knn[m] & (CN1-1);
    u32 v = atomicAdd(&offsets[n1], 1u);
    u32 pos = (v >> 6) + (v & 63u);
    csr[pos & (CM-1)] = (u32)m;
}

// ---------------------------------------------------------------------------
// k_dense: THREAD per dense point (max MLP on the gathers) + LDS-transposed
// coalesced epilogue (keeps WRITE_SIZE at the 64 MB ideal).
// ---------------------------------------------------------------------------
__global__ __launch_bounds__(256) void k_dense(
    const void* __restrict__ x1, const float* __restrict__ wb,
    const float* __restrict__ logits, const u16* __restrict__ upfeat,
    const u32* __restrict__ offsets, const u32* __restrict__ csr,
    void* __restrict__ out)
{
    __shared__ float lds[64][68];   // 64 rows, +4 pad: float4-aligned, 2-way banks (free)
    int bf  = (int)((const u32*)wb)[W_MODE];
    int tid = threadIdx.x;
    int n1  = blockIdx.x * 256 + tid;

    u32 pk = offsets[n1];
    int d = (int)(pk & 63u);
    int start = (int)(pk >> 6);

    float mx = -3.0e38f;
    for (int e = 0; e < d; e++) {
        u32 m = csr[(u32)(start + e) & (CM-1)] & (CM-1);
        mx = fmaxf(mx, logits[m]);
    }

    float acc[64];
    #pragma unroll
    for (int c = 0; c < 64; c++) acc[c] = 0.f;
    float denom = 0.f;
    for (int e = 0; e < d; e++) {
        u32 m = csr[(u32)(start + e) & (CM-1)] & (CM-1);
        float ex = __expf(logits[m] - mx);
        denom += ex;
        const uint4* uf = (const uint4*)(upfeat + (size_t)(m >> 4) * 64);
        #pragma unroll
        for (int q = 0; q < 8; q++) {
            uint4 u = uf[q];
            u32 w[4] = {u.x, u.y, u.z, u.w};
            #pragma unroll
            for (int e2 = 0; e2 < 4; e2++) {
                acc[q*8 + e2*2 + 0] = fmaf(ex, b2f((u16)(w[e2] & 0xffffu)), acc[q*8 + e2*2 + 0]);
                acc[q*8 + e2*2 + 1] = fmaf(ex, b2f((u16)(w[e2] >> 16)),     acc[q*8 + e2*2 + 1]);
            }
        }
    }
    float invd = (d > 0) ? (1.f / denom) : 0.f;

    float xr[64];
    load_row64(x1, (size_t)n1, bf, xr);

    for (int c = 0; c < 64; c++) {
        const float* wr = wb + W_W1 + c*64;   // uniform -> s_load
        float d0=0,d1=0,d2=0,d3=0;
        #pragma unroll
        for (int q = 0; q < 16; q++) {
            d0 = fmaf(xr[q*4+0], wr[q*4+0], d0);
            d1 = fmaf(xr[q*4+1], wr[q*4+1], d1);
            d2 = fmaf(xr[q*4+2], wr[q*4+2], d2);
            d3 = fmaf(xr[q*4+3], wr[q*4+3], d3);
        }
        float dt = (d0+d1)+(d2+d3);
        float y = fmaxf(fmaf(dt, wb[W_A1+c], wb[W_B1+c]), 0.f);
        acc[c] = y + acc[c] * invd;
    }

    // LDS-transposed coalesced epilogue: 4 chunks of 64 rows
    int row = tid >> 2, seg = tid & 3;
    for (int ch = 0; ch < 4; ch++) {
        __syncthreads();
        if ((tid >> 6) == ch) {
            int r = tid & 63;
            #pragma unroll
            for (int c = 0; c < 64; c++) lds[r][c] = acc[c];
        }
        __syncthreads();
        size_t orow = (size_t)(blockIdx.x * 256 + ch * 64 + row) * 64 + seg * 16;
        if (bf) {
            u32* ob = (u32*)((u16*)out + orow);
            #pragma unroll
            for (int i = 0; i < 8; i++) {
                float a = lds[row][seg*16 + i*2 + 0];
                float b = lds[row][seg*16 + i*2 + 1];
                ob[i] = (u32)f2b(a) | ((u32)f2b(b) << 16);
            }
        } else {
            float4* ov = (float4*)((float*)out + orow);
            #pragma unroll
            for (int i = 0; i < 4; i++) {
                float4 t;
                t.x = lds[row][seg*16 + i*4 + 0];
                t.y = lds[row][seg*16 + i*4 + 1];
                t.z = lds[row][seg*16 + i*4 + 2];
                t.w = lds[row][seg*16 + i*4 + 3];
                ov[i] = t;
            }
        }
    }
}

// ---------------------------------------------------------------------------
// Workspace layout (byte offsets) — total ~18.02 MiB:
//   wb      @ 0        (f32 weights + mode flag)
//   logits  @ 1  MiB   (4 MiB,  f32[M])
//   csr     @ 5  MiB   (4 MiB,  u32[M])
//   upfeat  @ 9  MiB   (8 MiB,  bf16[N2*64])
//   offsets @ 17 MiB   (1 MiB,  u32[N1], packed start<<6|count)
//   cursor  @ 18 MiB   (4 B)
// ---------------------------------------------------------------------------
extern "C" void kernel_launch(void* const* d_in, const int* in_sizes, int n_in,
                              void* d_out, int out_size, void* d_ws, size_t ws_size,
                              hipStream_t stream)
{
    (void)in_sizes; (void)n_in; (void)out_size; (void)ws_size;
    const void* p1   = d_in[0];
    const void* p2   = d_in[1];
    const void* x1   = d_in[2];
    const void* x2   = d_in[3];
    const int*  knn  = (const int*)d_in[4];
    const void* w1   = d_in[5];
    const void* b1   = d_in[6];
    const void* g1   = d_in[7];
    const void* be1  = d_in[8];
    const void* m1   = d_in[9];
    const void* v1   = d_in[10];
    const void* w2   = d_in[11];
    const void* b2   = d_in[12];
    const void* g2   = d_in[13];
    const void* be2  = d_in[14];
    const void* m2   = d_in[15];
    const void* v2   = d_in[16];
    const void* ws1  = d_in[17];
    const void* bs1  = d_in[18];
    const void* gs   = d_in[19];
    const void* bes  = d_in[20];
    const void* ms   = d_in[21];
    const void* vs   = d_in[22];
    const void* ws2w = d_in[23];
    const void* bs2  = d_in[24];

    char* ws = (char*)d_ws;
    float* wb      = (float*)(ws);
    float* logits  = (float*)(ws + ((size_t)1  << 20));
    u32*   csr     = (u32*)  (ws + ((size_t)5  << 20));
    u16*   upfeat  = (u16*)  (ws + ((size_t)9  << 20));
    u32*   offsets = (u32*)  (ws + ((size_t)17 << 20));
    u32*   cursor  = (u32*)  (ws + ((size_t)18 << 20));

    k_prep   <<<1 + CN1/256,     256, 0, stream>>>(w1,b1,g1,be1,m1,v1,
                                                   w2,b2,g2,be2,m2,v2,
                                                   ws1,bs1,gs,bes,ms,vs,
                                                   ws2w, bs2, wb, offsets, cursor);
    k_coarse <<<CN2/256,         256, 0, stream>>>(p1, p2, x2, knn, wb, logits, offsets);
    k_up     <<<CN2/(4*UP_PTS),  256, 0, stream>>>(x2, wb, upfeat);
    k_scan   <<<CN1/256,         256, 0, stream>>>(offsets, cursor);
    k_scatter<<<CM/256,          256, 0, stream>>>(knn, offsets, csr);
    k_dense  <<<CN1/256,         256, 0, stream>>>(x1, wb, logits, upfeat, offsets, csr, d_out);
}